// Round 1
// baseline (346.067 us; speedup 1.0000x reference)
//
#include <hip/hip_runtime.h>
#include <hip/hip_bf16.h>
#include <math.h>

typedef _Float16 half8 __attribute__((ext_vector_type(8)));
typedef float    f32x4 __attribute__((ext_vector_type(4)));
typedef int      i32x4 __attribute__((ext_vector_type(4)));

#define NPTS  50000
#define BATCH 8

// ---------------- weight prep: fp32 -> f16, 8 uniform [128][128] slots ----------------
// slot 0: w_lin0 [128][92] padded to [128][128] (cols 92.. = 0)   (K used = 96)
// slot 1..6: w_deform[j] [128][128]
// slot 7: w_lin1a [3][128] padded to [128][128] (rows 3.. = 0)    (N used = 16)
__global__ void prep_weights_k(const float* __restrict__ w_lin0,
                               const float* __restrict__ w_def,
                               const float* __restrict__ w1a,
                               _Float16* __restrict__ W)
{
    int stride = gridDim.x * blockDim.x;
    for (int idx = blockIdx.x * blockDim.x + threadIdx.x; idx < 8*128*128; idx += stride) {
        int slot = idx >> 14;
        int o    = (idx >> 7) & 127;
        int k    = idx & 127;
        float v = 0.f;
        if (slot == 0)      { if (k < 92) v = w_lin0[o*92 + k]; }
        else if (slot <= 6) { v = w_def[(slot-1)*16384 + o*128 + k]; }
        else                { if (o < 3) v = w1a[o*128 + k]; }
        W[idx] = (_Float16)v;
    }
}

// ---------------- fused decoder ----------------
// block: 512 threads (8 waves), 32 n-points x 8 batches = 256 rows.
// LDS: x [256 rows][256B f16, XOR-swizzled]  = 64KB
//      W double buffer 2 x [128][256B, swz]  = 64KB
__global__ __launch_bounds__(512, 2)
void decoder_main(const float* __restrict__ z0,
                  const float* __restrict__ cons,
                  const _Float16* __restrict__ W,
                  const float* __restrict__ w1b,
                  float* __restrict__ out)
{
    __shared__ __align__(16) unsigned char smem[131072];
    unsigned char* xb = smem;
    unsigned char* wbuf0 = smem + 65536;
    unsigned char* wbuf1 = smem + 98304;
    float* res_lds = (float*)(smem + 65536);   // reuse wbuf0 after layer 6

    const int t    = threadIdx.x;
    const int lane = t & 63;
    const int wid  = t >> 6;
    const int lrow = lane & 15;
    const int g    = lane >> 4;
    const int n0   = blockIdx.x * 32;

    // ---- stage helper: linear LDS dest, inverse-swizzled global source ----
    auto stage = [&](int slot, unsigned char* dst) {
        const unsigned char* src = (const unsigned char*)(W + slot*16384);
        #pragma unroll
        for (int r = 0; r < 4; ++r) {
            int L  = t*16 + r*8192;
            int o  = L >> 8;
            int kb = L & 255;
            i32x4 v = *(const i32x4*)(src + o*256 + (kb ^ ((o&7)<<4)));
            *(i32x4*)(dst + L) = v;
        }
    };

    // ---- build layer-0 input: [posenc60 | z32 | pad4], K=96 ----
    {
        int row = t >> 1;
        int k0  = (t & 1) * 48;
        int n   = n0 + (row >> 3); if (n >= NPTS) n = NPTS - 1;
        int b   = row & 7;
        float c0 = cons[n*3+0], c1 = cons[n*3+1], c2 = cons[n*3+2];
        #pragma unroll
        for (int ch = 0; ch < 6; ++ch) {
            int kc = k0 + ch*8;
            half8 h;
            #pragma unroll
            for (int jj = 0; jj < 8; ++jj) {
                int k = kc + jj;
                float v;
                if (k < 60) {
                    int c = k / 20, rem = k % 20, i = rem % 10;
                    float f   = exp2f(7.f - 7.f*(float)i/9.f);
                    float cc  = (c == 0) ? c0 : (c == 1) ? c1 : c2;
                    float arg = cc * f;
                    v = (rem < 10) ? sinf(arg) : cosf(arg);
                } else if (k < 92) {
                    v = z0[b*32 + (k-60)];
                } else {
                    v = 0.f;
                }
                h[jj] = (_Float16)v;
            }
            int byte = row*256 + ((kc*2) ^ ((row&7)<<4));
            *(half8*)(xb + byte) = h;
        }
    }
    stage(0, wbuf0);
    __syncthreads();

    const int arow0 = wid*32 + lrow;
    const int arow1 = arow0 + 16;
    const int s0 = (arow0 & 7) << 4;
    const int s1 = (arow1 & 7) << 4;

    // ---- layers 0..6 (lin0 + 6 deform) ----
    for (int j = 0; j < 7; ++j) {
        f32x4 acc[2][8];
        #pragma unroll
        for (int mt = 0; mt < 2; ++mt)
            #pragma unroll
            for (int nt = 0; nt < 8; ++nt)
                acc[mt][nt] = f32x4{0.f, 0.f, 0.f, 0.f};

        const unsigned char* wcur = (j & 1) ? wbuf1 : wbuf0;
        int nks = (j == 0) ? 3 : 4;
        for (int ks = 0; ks < nks; ++ks) {
            int koff = ks*64 + g*16;
            half8 a0 = *(const half8*)(xb + arow0*256 + (koff ^ s0));
            half8 a1 = *(const half8*)(xb + arow1*256 + (koff ^ s1));
            #pragma unroll
            for (int nt = 0; nt < 8; ++nt) {
                int bcol = nt*16 + lrow;
                half8 bf = *(const half8*)(wcur + bcol*256 + (koff ^ ((bcol&7)<<4)));
                acc[0][nt] = __builtin_amdgcn_mfma_f32_16x16x32_f16(a0, bf, acc[0][nt], 0, 0, 0);
                acc[1][nt] = __builtin_amdgcn_mfma_f32_16x16x32_f16(a1, bf, acc[1][nt], 0, 0, 0);
            }
        }

        // prefetch next layer's weights into the other buffer
        stage(j + 1, ((j + 1) & 1) ? wbuf1 : wbuf0);
        __syncthreads();   // all waves done reading xb / done staging

        // activation (none for j==0) + cvt + scatter back as next A operand
        #pragma unroll
        for (int mt = 0; mt < 2; ++mt) {
            int rbase = wid*32 + mt*16 + 4*g;
            #pragma unroll
            for (int nt = 0; nt < 8; ++nt) {
                int h = nt*16 + lrow;
                #pragma unroll
                for (int reg = 0; reg < 4; ++reg) {
                    float v = acc[mt][nt][reg];
                    if (j > 0) v = (v > 0.f) ? v : (__expf(v) - 1.f);
                    int row  = rbase + reg;
                    int byte = row*256 + ((h*2) ^ ((row&7)<<4));
                    *(_Float16*)(xb + byte) = (_Float16)v;
                }
            }
        }
        __syncthreads();
    }

    // ---- lin1a: N=16 (3 useful), K=128, ELU ----
    {
        f32x4 a2[2] = { f32x4{0.f,0.f,0.f,0.f}, f32x4{0.f,0.f,0.f,0.f} };
        const unsigned char* wcur = wbuf1;   // slot 7 staged at j==6
        for (int ks = 0; ks < 4; ++ks) {
            int koff = ks*64 + g*16;
            half8 a0 = *(const half8*)(xb + arow0*256 + (koff ^ s0));
            half8 a1 = *(const half8*)(xb + arow1*256 + (koff ^ s1));
            int bcol = lrow;
            half8 bf = *(const half8*)(wcur + bcol*256 + (koff ^ ((bcol&7)<<4)));
            a2[0] = __builtin_amdgcn_mfma_f32_16x16x32_f16(a0, bf, a2[0], 0, 0, 0);
            a2[1] = __builtin_amdgcn_mfma_f32_16x16x32_f16(a1, bf, a2[1], 0, 0, 0);
        }
        // write res (3 cols) to LDS fp32; wbuf0 is free (last read at j==6, two barriers ago)
        if (lrow < 3) {
            #pragma unroll
            for (int mt = 0; mt < 2; ++mt) {
                int rbase = wid*32 + mt*16 + 4*g;
                #pragma unroll
                for (int reg = 0; reg < 4; ++reg) {
                    float v = (mt == 0) ? a2[0][reg] : a2[1][reg];
                    v = (v > 0.f) ? v : (__expf(v) - 1.f);
                    res_lds[(rbase + reg)*4 + lrow] = v;
                }
            }
        }
    }
    __syncthreads();

    // ---- lin1b (3x3) + pos/resn writes, coalesced per batch ----
    for (int idx = t; idx < 768; idx += 512) {
        int b  = idx / 96;
        int r  = idx % 96;
        int ln = r / 3;
        int i  = r % 3;
        int row = ln*8 + b;
        float rv = w1b[i*3+0]*res_lds[row*4+0]
                 + w1b[i*3+1]*res_lds[row*4+1]
                 + w1b[i*3+2]*res_lds[row*4+2];
        int n = n0 + ln;
        if (n < NPTS) {
            out[(b*NPTS + n)*3 + i]                 = cons[n*3+i] + rv;
            out[BATCH*NPTS*3 + (b*NPTS + n)*3 + i]  = rv;
        }
    }
}

extern "C" void kernel_launch(void* const* d_in, const int* in_sizes, int n_in,
                              void* d_out, int out_size, void* d_ws, size_t ws_size,
                              hipStream_t stream)
{
    const float* z0     = (const float*)d_in[0];
    const float* cons   = (const float*)d_in[1];
    const float* w_lin0 = (const float*)d_in[2];
    const float* w_def  = (const float*)d_in[3];
    const float* w1a    = (const float*)d_in[4];
    const float* w1b    = (const float*)d_in[5];
    _Float16* W = (_Float16*)d_ws;   // 8 slots * 16384 f16 = 256 KB

    prep_weights_k<<<64, 256, 0, stream>>>(w_lin0, w_def, w1a, W);
    int nblk = (NPTS + 31) / 32;     // 1563
    decoder_main<<<nblk, 512, 0, stream>>>(z0, cons, W, w1b, (float*)d_out);
}

// Round 2
// 200.927 us; speedup vs baseline: 1.7223x; 1.7223x over previous
//
#include <hip/hip_runtime.h>
#include <hip/hip_bf16.h>
#include <math.h>

typedef _Float16 half8 __attribute__((ext_vector_type(8)));
typedef float    f32x4 __attribute__((ext_vector_type(4)));

#define NPTS  50000
#define BATCH 8

// direct global->LDS (16B per lane). LDS dest must be wave-uniform base + lane*16.
__device__ __forceinline__ void gload_lds16(const void* g, void* l) {
    __builtin_amdgcn_global_load_lds(
        (const __attribute__((address_space(1))) unsigned int*)g,
        (__attribute__((address_space(3))) unsigned int*)l, 16, 0, 0);
}

// ---------------- weight prep ----------------
// 8 slots of [128 rows o][128 positions], f16.
// Column PERMUTATION pi: pos=(ks,g,j) -> k = ks*32 + 16*(j>>2) + 4*g + (j&3).
// This makes the D-accumulator registers of layer j directly usable (after
// ELU+pack) as the B-fragment of layer j+1 -- no LDS round trip for x.
// Slot 0 input semantic order: [pe(60) | pad4 | z(32) | pad32]  (K=128).
// Slots 1..6: w_deform. Slot 7: w_lin1a padded to 128 rows (3 used).
// On top, the LDS XOR-swizzle pre-permutation: f16pos ^= (o&7)<<3.
__global__ void prep_weights_k(const float* __restrict__ w_lin0,
                               const float* __restrict__ w_def,
                               const float* __restrict__ w1a,
                               _Float16* __restrict__ W)
{
    int idx = blockIdx.x * blockDim.x + threadIdx.x;
    if (idx >= 8*128*128) return;
    int slot = idx >> 14;
    int o    = (idx >> 7) & 127;
    int pos  = idx & 127;
    int ks = pos >> 5, l = pos & 31, gg = l >> 3, jj = l & 7;
    int k = ks*32 + 16*(jj>>2) + 4*gg + (jj&3);
    float v = 0.f;
    if (slot == 0) {
        if (k < 60)                 v = w_lin0[o*92 + k];
        else if (k >= 64 && k < 96) v = w_lin0[o*92 + 60 + (k-64)];
    } else if (slot <= 6) {
        v = w_def[(slot-1)*16384 + o*128 + k];
    } else {
        if (o < 3) v = w1a[o*128 + k];
    }
    int pos_sw = pos ^ ((o & 7) << 3);   // bank-conflict swizzle (16B granules)
    W[slot*16384 + o*128 + pos_sw] = (_Float16)v;
}

// ---------------- fused decoder ----------------
// 256 threads = 4 waves. Each wave owns 64 rows (rows = n_local*8 + b),
// all 128 features, entirely in registers. LDS = W double buffer only (64KB).
__global__ __launch_bounds__(256, 2)
void decoder_main(const float* __restrict__ z0,
                  const float* __restrict__ cons,
                  const _Float16* __restrict__ W,
                  const float* __restrict__ w1b,
                  float* __restrict__ out)
{
    __shared__ __align__(16) unsigned char smem[65536];   // 2 x 32KB W buffers
    float* res_f = (float*)smem;                          // reuse buf0 at epilogue

    const int t    = threadIdx.x;
    const int lane = t & 63;
    const int wid  = t >> 6;
    const int p    = lane & 15;
    const int g    = lane >> 4;
    const int n0   = blockIdx.x * 32;

    auto stage = [&](int slot, int buf) {
        const unsigned char* src = (const unsigned char*)(W + slot*16384) + t*16;
        unsigned char* dst = smem + buf*32768 + t*16;
        #pragma unroll
        for (int i = 0; i < 8; ++i)
            gload_lds16(src + i*4096, dst + i*4096);
    };

    stage(0, 0);   // W slot 0 -> buf0 (latency hides under x0 build)

    // ---- build layer-0 B-fragments in pi-position order, in registers ----
    half8 Bw[4][4];
    #pragma unroll
    for (int pt = 0; pt < 4; ++pt) {
        int lrow = wid*64 + pt*16 + p;
        int n = n0 + (lrow >> 3); if (n >= NPTS) n = NPTS - 1;
        int b = lrow & 7;
        float c0 = cons[n*3+0], c1 = cons[n*3+1], c2 = cons[n*3+2];
        #pragma unroll
        for (int ks = 0; ks < 2; ++ks) {        // positions 0..63: posenc region
            half8 h;
            #pragma unroll
            for (int j = 0; j < 8; ++j) {
                int k = ks*32 + 16*(j>>2) + 4*g + (j&3);
                float v = 0.f;
                if (k < 60) {
                    int c = k/20, rem = k%20, i = rem%10;
                    float f  = exp2f(7.f * (1.f - (float)i * (1.f/9.f)));
                    float cc = (c == 0) ? c0 : (c == 1) ? c1 : c2;
                    float a  = cc * f;
                    v = (rem < 10) ? __sinf(a) : __cosf(a);
                }
                h[j] = (_Float16)v;
            }
            Bw[pt][ks] = h;
        }
        {   // ks=2: z region (k_sem = 64 + k_local)
            half8 h;
            #pragma unroll
            for (int j = 0; j < 8; ++j) {
                int zi = 16*(j>>2) + 4*g + (j&3);
                h[j] = (_Float16)z0[b*32 + zi];
            }
            Bw[pt][2] = h;
        }
        {   // ks=3: zero pad (slot0 cols 96..127 are zero too)
            half8 h;
            #pragma unroll
            for (int j = 0; j < 8; ++j) h[j] = (_Float16)0.f;
            Bw[pt][3] = h;
        }
    }

    __syncthreads();     // drains stage(0)
    stage(1, 1);

    // ---- layers 0..6: lin0 + 6 deform, x fully in registers ----
    for (int j = 0; j < 7; ++j) {
        const unsigned char* wb = smem + (j & 1)*32768;
        f32x4 acc[4][8];
        #pragma unroll
        for (int pt = 0; pt < 4; ++pt)
            #pragma unroll
            for (int ft = 0; ft < 8; ++ft)
                acc[pt][ft] = f32x4{0.f, 0.f, 0.f, 0.f};

        #pragma unroll
        for (int ft = 0; ft < 8; ++ft) {
            int row = ft*16 + p;
            int sw  = (row & 7) << 4;
            half8 A[4];
            #pragma unroll
            for (int ks = 0; ks < 4; ++ks)
                A[ks] = *(const half8*)(wb + row*256 + ((ks*64 + g*16) ^ sw));
            #pragma unroll
            for (int ks = 0; ks < 4; ++ks)
                #pragma unroll
                for (int pt = 0; pt < 4; ++pt)
                    acc[pt][ft] = __builtin_amdgcn_mfma_f32_16x16x32_f16(
                        A[ks], Bw[pt][ks], acc[pt][ft], 0, 0, 0);
        }

        __syncthreads();            // all waves done reading wb; stage(j+1) landed
        if (j <= 5) stage(j + 2, j & 1);   // overwrite freed buffer

        // activation + pack: acc -> next layer's B-fragments (pure in-lane)
        #pragma unroll
        for (int pt = 0; pt < 4; ++pt) {
            #pragma unroll
            for (int ks = 0; ks < 4; ++ks) {
                half8 h;
                #pragma unroll
                for (int e = 0; e < 4; ++e) {
                    float v = acc[pt][2*ks][e];
                    v = (j == 0 || v > 0.f) ? v : (__expf(v) - 1.f);
                    h[e] = (_Float16)v;
                }
                #pragma unroll
                for (int e = 0; e < 4; ++e) {
                    float v = acc[pt][2*ks+1][e];
                    v = (j == 0 || v > 0.f) ? v : (__expf(v) - 1.f);
                    h[4+e] = (_Float16)v;
                }
                Bw[pt][ks] = h;
            }
        }
    }

    // ---- lin1a: slot 7 in buf1, 16 output rows (3 used), ELU ----
    {
        const unsigned char* wb = smem + 32768;
        f32x4 a1[4];
        #pragma unroll
        for (int pt = 0; pt < 4; ++pt) a1[pt] = f32x4{0.f, 0.f, 0.f, 0.f};
        int row = p;
        int sw  = (row & 7) << 4;
        half8 A[4];
        #pragma unroll
        for (int ks = 0; ks < 4; ++ks)
            A[ks] = *(const half8*)(wb + row*256 + ((ks*64 + g*16) ^ sw));
        #pragma unroll
        for (int ks = 0; ks < 4; ++ks)
            #pragma unroll
            for (int pt = 0; pt < 4; ++pt)
                a1[pt] = __builtin_amdgcn_mfma_f32_16x16x32_f16(
                    A[ks], Bw[pt][ks], a1[pt], 0, 0, 0);

        // lanes g==0 hold feats 0..3 for their point-row; keep 0..2 (ELU'd)
        if (g == 0) {
            #pragma unroll
            for (int pt = 0; pt < 4; ++pt) {
                int lrow = wid*64 + pt*16 + p;
                #pragma unroll
                for (int e = 0; e < 3; ++e) {
                    float v = a1[pt][e];
                    v = (v > 0.f) ? v : (__expf(v) - 1.f);
                    res_f[lrow*3 + e] = v;
                }
            }
        }
    }
    __syncthreads();

    // ---- lin1b (3x3) + coalesced pos/resn writes ----
    for (int idx = t; idx < 1536; idx += 256) {
        int arr = idx >> 9 >= 1 ? (idx >= 768) : 0;  // arr = idx/768
        arr = idx / 768;
        int e  = idx % 768;
        int b  = e / 96;
        int q  = e % 96;
        int nl = q / 3;
        int i  = q % 3;
        int rowl = nl*8 + b;
        float r0 = res_f[rowl*3+0], r1 = res_f[rowl*3+1], r2 = res_f[rowl*3+2];
        float rv = w1b[i*3+0]*r0 + w1b[i*3+1]*r1 + w1b[i*3+2]*r2;
        int n = n0 + nl;
        if (n < NPTS) {
            if (arr) out[BATCH*NPTS*3 + (b*NPTS + n)*3 + i] = rv;
            else     out[(b*NPTS + n)*3 + i] = cons[n*3+i] + rv;
        }
    }
}

extern "C" void kernel_launch(void* const* d_in, const int* in_sizes, int n_in,
                              void* d_out, int out_size, void* d_ws, size_t ws_size,
                              hipStream_t stream)
{
    const float* z0     = (const float*)d_in[0];
    const float* cons   = (const float*)d_in[1];
    const float* w_lin0 = (const float*)d_in[2];
    const float* w_def  = (const float*)d_in[3];
    const float* w1a    = (const float*)d_in[4];
    const float* w1b    = (const float*)d_in[5];
    _Float16* W = (_Float16*)d_ws;   // 8 slots * 16384 f16 = 256 KB

    prep_weights_k<<<(8*128*128 + 255)/256, 256, 0, stream>>>(w_lin0, w_def, w1a, W);
    int nblk = (NPTS + 31) / 32;     // 1563 blocks * 256 rows
    decoder_main<<<nblk, 256, 0, stream>>>(z0, cons, W, w1b, (float*)d_out);
}